// Round 3
// baseline (42.634 us; speedup 1.0000x reference)
//
#include <hip/hip_runtime.h>
#include <math.h>

#define D    512
#define NW   4                       // waves per block (independent, no barriers)
#define NIT  2                       // items per wave, pipelined
#define SWZ(f) ((f) ^ (((f) >> 3) & 7))   // bank-group swizzle on float4 slots

__device__ __forceinline__ float4 f4add(float4 a, float4 b) {
    return make_float4(a.x + b.x, a.y + b.y, a.z + b.z, a.w + b.w);
}

// per-lane: acc[u] = sum over its j-half of a[j]*bb[512+j-16g-u], u=0..15
__device__ __forceinline__ void corr16(const float4* __restrict__ ap,
                                       const float4* __restrict__ bbp,
                                       int g, int jh, float* __restrict__ acc)
{
    #pragma unroll
    for (int u = 0; u < 16; ++u) acc[u] = 0.f;

    float wA[16], wB[16];
    int fb = 128 + (jh << 6) - (g << 2);   // float4 slot of window start
    int jc = (jh << 6);                    // a slot base

    #pragma unroll
    for (int q = 0; q < 4; ++q) {          // prologue: floats [J0-16g-16, +16)
        const float4 t = bbp[SWZ(fb - 4 + q)];
        wA[4*q+0]=t.x; wA[4*q+1]=t.y; wA[4*q+2]=t.z; wA[4*q+3]=t.w;
    }

    float4 pb[4], pa[4], qb[4], qa[4];

#define PRELOAD(B, A)                                   \
    do { _Pragma("unroll")                              \
        for (int q = 0; q < 4; ++q) {                   \
            B[q] = bbp[SWZ(fb + q)];                    \
            A[q] = ap[jc + q];                          \
        } fb += 4; jc += 4;                             \
    } while (0)

#define COMPUTE(B, A, WOLD, WNEW)                                       \
    do {                                                                \
        float av[16];                                                   \
        _Pragma("unroll")                                               \
        for (int q = 0; q < 4; ++q) {                                   \
            WNEW[4*q+0]=B[q].x; WNEW[4*q+1]=B[q].y;                     \
            WNEW[4*q+2]=B[q].z; WNEW[4*q+3]=B[q].w;                     \
            av[4*q+0]=A[q].x; av[4*q+1]=A[q].y;                         \
            av[4*q+2]=A[q].z; av[4*q+3]=A[q].w;                         \
        }                                                               \
        _Pragma("unroll")                                               \
        for (int c = 0; c < 16; ++c) {                                  \
            _Pragma("unroll")                                           \
            for (int u = 0; u < 16; ++u) {                              \
                const int wi = 16 + c - u; /* in [1,31] */              \
                acc[u] += av[c] * ((wi < 16) ? WOLD[wi] : WNEW[wi-16]); \
            }                                                           \
        }                                                               \
    } while (0)

    PRELOAD(pb, pa);                        // step 0 in flight
    #pragma unroll 1
    for (int kk = 0; kk < 7; ++kk) {
        PRELOAD(qb, qa);                    // step 2kk+1 in flight
        COMPUTE(pb, pa, wA, wB);            // step 2kk
        PRELOAD(pb, pa);                    // step 2kk+2 in flight
        COMPUTE(qb, qa, wB, wA);            // step 2kk+1
    }
    PRELOAD(qb, qa);                        // step 15 in flight
    COMPUTE(pb, pa, wA, wB);                // step 14
    COMPUTE(qb, qa, wB, wA);                // step 15
#undef PRELOAD
#undef COMPUTE
}

__global__ __launch_bounds__(NW * 64, 2) void hole_score_kernel(
    const float* __restrict__ ew, const float* __restrict__ eb,
    const float* __restrict__ rw, const float* __restrict__ rb,
    const int* __restrict__ xs, const int* __restrict__ ys,
    const int* __restrict__ rs, float* __restrict__ out)
{
    // per wave, per buffer: [0..127] = a (linear), [128..383] = bb (swizzled, doubled)
    __shared__ float4 smem[NW][2][384];

    const int w  = threadIdx.x >> 6;
    const int l  = threadIdx.x & 63;
    const int g  = l & 31;                 // owns shifts [16g, 16g+16)
    const int jh = l >> 5;                 // j-half
    const int i0 = blockIdx.x * (NW * NIT) + w * NIT;

    // all indices up-front
    const int x0 = xs[i0],     y0 = ys[i0],     r0 = rs[i0];
    const int x1 = xs[i0 + 1], y1 = ys[i0 + 1], r1 = rs[i0 + 1];

    // ---- gather item0 rows (coalesced float4) ----
    const float4* exw0 = (const float4*)(ew + (size_t)x0 * D);
    const float4* exb0 = (const float4*)(eb + (size_t)x0 * D);
    const float4* eyw0 = (const float4*)(ew + (size_t)y0 * D);
    const float4* eyb0 = (const float4*)(eb + (size_t)y0 * D);
    float4 a00 = exw0[l], a01 = exw0[l + 64];
    float4 a10 = exb0[l], a11 = exb0[l + 64];
    float4 b00 = eyw0[l], b01 = eyw0[l + 64];
    float4 b10 = eyb0[l], b11 = eyb0[l + 64];

    // rel row item0, epilogue slots for this lane (latency hidden under compute0)
    const float4* rw0 = (const float4*)(rw + (size_t)r0 * D);
    const float4* rb0 = (const float4*)(rb + (size_t)r0 * D);
    float4 rA0[4], rB0[4];
    #pragma unroll
    for (int q = 0; q < 4; ++q) { rA0[q] = rw0[(g << 2) + q]; rB0[q] = rb0[(g << 2) + q]; }

    // ---- stage item0 into buf0 ----
    float4* sa0  = &smem[w][0][0];
    float4* sbb0 = sa0 + 128;
    sa0[l]      = f4add(a00, a10);
    sa0[l + 64] = f4add(a01, a11);
    {
        float4 v0 = f4add(b00, b10), v1 = f4add(b01, b11);
        sbb0[SWZ(l)]            = v0;    // SWZ(f+64)=SWZ(f)+64, SWZ(f+128)=SWZ(f)+128
        sbb0[SWZ(l + 64)]       = v1;
        sbb0[SWZ(l) + 128]      = v0;
        sbb0[SWZ(l + 64) + 128] = v1;
    }

    // ---- issue item1 gather NOW; latency hides under compute0 ----
    const float4* exw1 = (const float4*)(ew + (size_t)x1 * D);
    const float4* exb1 = (const float4*)(eb + (size_t)x1 * D);
    const float4* eyw1 = (const float4*)(ew + (size_t)y1 * D);
    const float4* eyb1 = (const float4*)(eb + (size_t)y1 * D);
    float4 c00 = exw1[l], c01 = exw1[l + 64];
    float4 c10 = exb1[l], c11 = exb1[l + 64];
    float4 d00 = eyw1[l], d01 = eyw1[l + 64];
    float4 d10 = eyb1[l], d11 = eyb1[l + 64];

    // ---- compute item0 ----
    float acc[16];
    corr16(sa0, sbb0, g, jh, acc);
    float part = 0.f;
    #pragma unroll
    for (int q = 0; q < 4; ++q) {
        part += (rA0[q].x + rB0[q].x) * acc[4*q+0]
              + (rA0[q].y + rB0[q].y) * acc[4*q+1]
              + (rA0[q].z + rB0[q].z) * acc[4*q+2]
              + (rA0[q].w + rB0[q].w) * acc[4*q+3];
    }
    #pragma unroll
    for (int off = 32; off >= 1; off >>= 1) part += __shfl_down(part, off, 64);
    if (l == 0) out[i0] = 1.0f / (1.0f + expf(-part * (1.0f / (float)D)));

    // ---- stage item1 into buf1 ----
    float4* sa1  = &smem[w][1][0];
    float4* sbb1 = sa1 + 128;
    sa1[l]      = f4add(c00, c10);
    sa1[l + 64] = f4add(c01, c11);
    {
        float4 v0 = f4add(d00, d10), v1 = f4add(d01, d11);
        sbb1[SWZ(l)]            = v0;
        sbb1[SWZ(l + 64)]       = v1;
        sbb1[SWZ(l) + 128]      = v0;
        sbb1[SWZ(l + 64) + 128] = v1;
    }

    // rel row item1 (lazy; rel tables are 1 MB each -> L2/L3-hot)
    const float4* rw1 = (const float4*)(rw + (size_t)r1 * D);
    const float4* rb1 = (const float4*)(rb + (size_t)r1 * D);
    float4 rA1[4], rB1[4];
    #pragma unroll
    for (int q = 0; q < 4; ++q) { rA1[q] = rw1[(g << 2) + q]; rB1[q] = rb1[(g << 2) + q]; }

    // ---- compute item1 ----
    corr16(sa1, sbb1, g, jh, acc);
    part = 0.f;
    #pragma unroll
    for (int q = 0; q < 4; ++q) {
        part += (rA1[q].x + rB1[q].x) * acc[4*q+0]
              + (rA1[q].y + rB1[q].y) * acc[4*q+1]
              + (rA1[q].z + rB1[q].z) * acc[4*q+2]
              + (rA1[q].w + rB1[q].w) * acc[4*q+3];
    }
    #pragma unroll
    for (int off = 32; off >= 1; off >>= 1) part += __shfl_down(part, off, 64);
    if (l == 0) out[i0 + 1] = 1.0f / (1.0f + expf(-part * (1.0f / (float)D)));
}

extern "C" void kernel_launch(void* const* d_in, const int* in_sizes, int n_in,
                              void* d_out, int out_size, void* d_ws, size_t ws_size,
                              hipStream_t stream)
{
    const float* ew = (const float*)d_in[0];
    const float* eb = (const float*)d_in[1];
    const float* rw = (const float*)d_in[2];
    const float* rb = (const float*)d_in[3];
    const int*   xs = (const int*)d_in[4];
    const int*   ys = (const int*)d_in[5];
    const int*   rs = (const int*)d_in[6];
    float* out = (float*)d_out;

    const int batch = in_sizes[4];                 // 4096
    dim3 grid(batch / (NW * NIT)), block(NW * 64); // 512 x 256
    hole_score_kernel<<<grid, block, 0, stream>>>(ew, eb, rw, rb, xs, ys, rs, out);
}

// Round 5
// 29.474 us; speedup vs baseline: 1.4465x; 1.4465x over previous
//
#include <hip/hip_runtime.h>
#include <math.h>

#define D    512
#define NW   4                            // waves per block; 1 item per wave
#define SWZ(f) ((f) ^ (((f) >> 3) & 7))   // bank-group swizzle on float4 slots

typedef __fp16 h2 __attribute__((ext_vector_type(2)));

__device__ __forceinline__ h2 cvt2(float lo, float hi) {
    return __builtin_amdgcn_cvt_pkrtz(lo, hi);   // v_cvt_pkrtz_f16_f32
}
// O = (lo.hi, hi.lo): pair (w[2k+1], w[2k+2]) from aligned P[k], P[k+1]
__device__ __forceinline__ h2 oddpair(h2 hi, h2 lo) {
    unsigned u = __builtin_amdgcn_alignbit(__builtin_bit_cast(unsigned, hi),
                                           __builtin_bit_cast(unsigned, lo), 16);
    return __builtin_bit_cast(h2, u);
}

__global__ __launch_bounds__(NW * 64, 3) void hole_score_kernel(
    const float* __restrict__ ew, const float* __restrict__ eb,
    const float* __restrict__ rw, const float* __restrict__ rb,
    const int* __restrict__ xs, const int* __restrict__ ys,
    const int* __restrict__ rs, float* __restrict__ out)
{
    // per wave: [0..127] = a (linear), [128..383] = bb (doubled, swizzled)
    __shared__ float4 smem[NW][384];

    const int w    = threadIdx.x >> 6;
    const int l    = threadIdx.x & 63;
    const int g    = l & 31;              // owns shifts [16g, 16g+16)
    const int jh   = l >> 5;              // j-half
    const int item = blockIdx.x * NW + w;

    const int xi = xs[item], yi = ys[item], ri = rs[item];

    float4* sa  = smem[w];
    float4* sbb = sa + 128;

    // ---- gather + stage (wave-local LDS slice; no barrier needed) ----
    {
        const float4* xw = (const float4*)(ew + (size_t)xi * D);
        const float4* xb = (const float4*)(eb + (size_t)xi * D);
        const float4* yw = (const float4*)(ew + (size_t)yi * D);
        const float4* yb = (const float4*)(eb + (size_t)yi * D);
        float4 u0 = xw[l], u1 = xw[l + 64];
        float4 v0 = xb[l], v1 = xb[l + 64];
        float4 p0 = yw[l], p1 = yw[l + 64];
        float4 q0 = yb[l], q1 = yb[l + 64];
        sa[l]      = make_float4(u0.x+v0.x, u0.y+v0.y, u0.z+v0.z, u0.w+v0.w);
        sa[l + 64] = make_float4(u1.x+v1.x, u1.y+v1.y, u1.z+v1.z, u1.w+v1.w);
        float4 r0 = make_float4(p0.x+q0.x, p0.y+q0.y, p0.z+q0.z, p0.w+q0.w);
        float4 r1 = make_float4(p1.x+q1.x, p1.y+q1.y, p1.z+q1.z, p1.w+q1.w);
        sbb[SWZ(l)]            = r0;      // SWZ(f+64)=SWZ(f)+64, SWZ(f+128)=SWZ(f)+128
        sbb[SWZ(l + 64)]       = r1;
        sbb[SWZ(l) + 128]      = r0;
        sbb[SWZ(l + 64) + 128] = r1;
    }

    // ---- sliding-window correlation in packed f16, f32 accumulate ----
    // acc[u] = sum_{j in half} a[j] * bb[512 + j - 16g - u]
    float acc[16];
    #pragma unroll
    for (int u = 0; u < 16; ++u) acc[u] = 0.f;

    h2 PA[8], PB[8], OA[7], OB[7], A[8];
    int fb = 128 + (jh << 6) - (g << 2);   // float4 slot of new-half start
    int jc = (jh << 6);                    // a float4 slot base

    // prologue: old half w[0..15] = floats starting at slot fb-4
    #pragma unroll
    for (int q = 0; q < 4; ++q) {
        const float4 t = sbb[SWZ(fb - 4 + q)];
        PA[2*q]   = cvt2(t.x, t.y);
        PA[2*q+1] = cvt2(t.z, t.w);
    }
    #pragma unroll
    for (int k = 0; k < 7; ++k) OA[k] = oddpair(PA[k+1], PA[k]);

    // aligned pair i in [1,15]; odd pair i in [0,14]
#define PAL(PA_, PB_, i) ((i) < 8 ? PA_[i] : PB_[(i) - 8])
#define OPR(OA_, OB_, oa7_, i) ((i) < 7 ? OA_[i] : ((i) == 7 ? oa7_ : OB_[(i) - 8]))

#define STEP(PA_, OA_, PB_, OB_)                                            \
    do {                                                                    \
        float4 tb[4], ta[4];                                                \
        _Pragma("unroll")                                                   \
        for (int q = 0; q < 4; ++q) { tb[q] = sbb[SWZ(fb + q)]; ta[q] = sa[jc + q]; } \
        _Pragma("unroll")                                                   \
        for (int q = 0; q < 4; ++q) {                                       \
            PB_[2*q]   = cvt2(tb[q].x, tb[q].y);                            \
            PB_[2*q+1] = cvt2(tb[q].z, tb[q].w);                            \
            A[2*q]     = cvt2(ta[q].x, ta[q].y);                            \
            A[2*q+1]   = cvt2(ta[q].z, ta[q].w);                            \
        }                                                                   \
        const h2 oa7 = oddpair(PB_[0], PA_[7]);                             \
        _Pragma("unroll")                                                   \
        for (int k = 0; k < 7; ++k) OB_[k] = oddpair(PB_[k+1], PB_[k]);     \
        _Pragma("unroll")                                                   \
        for (int uu = 0; uu < 8; ++uu) {                                    \
            _Pragma("unroll")                                               \
            for (int cp = 0; cp < 8; ++cp) {                                \
                acc[2*uu] = __builtin_amdgcn_fdot2(A[cp],                   \
                    PAL(PA_, PB_, 8 + cp - uu), acc[2*uu], false);          \
                acc[2*uu+1] = __builtin_amdgcn_fdot2(A[cp],                 \
                    OPR(OA_, OB_, oa7, 7 + cp - uu), acc[2*uu+1], false);   \
            }                                                               \
        }                                                                   \
        fb += 4; jc += 4;                                                   \
    } while (0)

    #pragma unroll 1
    for (int kk = 0; kk < 8; ++kk) {       // 16 macro-steps, phase-alternated
        STEP(PA, OA, PB, OB);
        STEP(PB, OB, PA, OA);
    }
#undef STEP
#undef PAL
#undef OPR

    // ---- epilogue: rel dot (f32), wave reduce, sigmoid ----
    const float4* rwp = (const float4*)(rw + (size_t)ri * D);
    const float4* rbp = (const float4*)(rb + (size_t)ri * D);
    float part = 0.f;
    #pragma unroll
    for (int q = 0; q < 4; ++q) {
        const float4 rA = rwp[(g << 2) + q];
        const float4 rB = rbp[(g << 2) + q];
        part += (rA.x + rB.x) * acc[4*q+0]
              + (rA.y + rB.y) * acc[4*q+1]
              + (rA.z + rB.z) * acc[4*q+2]
              + (rA.w + rB.w) * acc[4*q+3];
    }
    #pragma unroll
    for (int off = 32; off >= 1; off >>= 1) part += __shfl_down(part, off, 64);

    if (l == 0)
        out[item] = 1.0f / (1.0f + expf(-part * (1.0f / (float)D)));
}

extern "C" void kernel_launch(void* const* d_in, const int* in_sizes, int n_in,
                              void* d_out, int out_size, void* d_ws, size_t ws_size,
                              hipStream_t stream)
{
    const float* ew = (const float*)d_in[0];
    const float* eb = (const float*)d_in[1];
    const float* rw = (const float*)d_in[2];
    const float* rb = (const float*)d_in[3];
    const int*   xs = (const int*)d_in[4];
    const int*   ys = (const int*)d_in[5];
    const int*   rs = (const int*)d_in[6];
    float* out = (float*)d_out;

    const int batch = in_sizes[4];          // 4096
    dim3 grid(batch / NW), block(NW * 64);
    hole_score_kernel<<<grid, block, 0, stream>>>(ew, eb, rw, rb, xs, ys, rs, out);
}